// Round 7
// baseline (141.970 us; speedup 1.0000x reference)
//
#include <hip/hip_runtime.h>
#include <hip/hip_bf16.h>

#define B_  8
#define C_  64
#define H_  256
#define W_  256
#define HW_ (H_ * W_)
#define NP_ 25          // NUM_POINTS
#define NA_ 28          // N + 3 (augmented TPS system size)
#define NRHS_ 16        // 8 batches x 2 coords
#define NCOL_ (NA_ + NRHS_)   // 44
#define PARTS_ 4              // chunks per channel
#define CHUNK_ (HW_ / PARTS_) // 16384 floats per chunk

typedef float f32x4 __attribute__((ext_vector_type(4)));

// ---------------------------------------------------------------------------
// Kernel 1: partial sums for per-(b,c) mean of concat([t, rgb]).
// 2048 blocks, fully resident; XCD-contiguous (bid&7 = XCD owns batch b=xcd).
// At the measured ~3.5 TB/s device read wall (268 MB -> ~77 us). Unchanged.
// ---------------------------------------------------------------------------
__global__ __launch_bounds__(256) void mean_partial_kernel(const float* __restrict__ t,
                                                           const float* __restrict__ rgb,
                                                           float* __restrict__ partial) {
    int bid   = blockIdx.x;            // 0..2047
    int xcd   = bid & 7;
    int li    = bid >> 3;              // 0..255 within XCD
    int plane = xcd * 64 + (li >> 2);  // = b*64 + c  (b == xcd)
    int part  = li & 3;
    int b = plane >> 6, c = plane & 63;

    size_t off = (size_t)plane * HW_ + (size_t)part * CHUNK_;
    const f32x4* t4 = (const f32x4*)(t + off);
    const f32x4* r4 = (const f32x4*)(rgb + off);
    int base = threadIdx.x;

    float at = 0.f, ar = 0.f;
    #pragma unroll
    for (int half = 0; half < 2; ++half) {
        f32x4 va[8], vb[8];
        #pragma unroll
        for (int k = 0; k < 8; ++k) va[k] = t4[base + (half * 8 + k) * 256];
        #pragma unroll
        for (int k = 0; k < 8; ++k) vb[k] = __builtin_nontemporal_load(r4 + base + (half * 8 + k) * 256);
        #pragma unroll
        for (int k = 0; k < 8; ++k) {
            at += (va[k].x + va[k].y) + (va[k].z + va[k].w);
            ar += (vb[k].x + vb[k].y) + (vb[k].z + vb[k].w);
        }
    }
    #pragma unroll
    for (int o = 32; o > 0; o >>= 1) {
        at += __shfl_down(at, o);
        ar += __shfl_down(ar, o);
    }
    __shared__ float redt[4], redr[4];
    if ((threadIdx.x & 63) == 0) {
        redt[threadIdx.x >> 6] = at;
        redr[threadIdx.x >> 6] = ar;
    }
    __syncthreads();
    if (threadIdx.x == 0) {
        // feat layout: [b][0:64]=mean(t), [b][64:128]=mean(rgb)
        partial[(b * 128 + c) * PARTS_ + part]      = (redt[0] + redt[1]) + (redt[2] + redt[3]);
        partial[(b * 128 + 64 + c) * PARTS_ + part] = (redr[0] + redr[1]) + (redr[2] + redr[3]);
    }
}

// ---------------------------------------------------------------------------
// Kernel 2: reduce partials -> feat; delta = feat @ fc_w^T + fc_b;
// cp = init_cp + delta (second output); build TPS L (28x28, f64) and
// Gauss-Jordan solve for all 8 batches x 2 coords -> Wm[8][28][2] f64 in ws.
// ---------------------------------------------------------------------------
__global__ __launch_bounds__(256) void solve_kernel(const float* __restrict__ partial,
                                                    const float* __restrict__ fc_w,
                                                    const float* __restrict__ fc_b,
                                                    const float* __restrict__ init_cp,
                                                    float* __restrict__ cp_out,
                                                    double* __restrict__ Wm) {
    __shared__ float  s_feat[B_ * 128];
    __shared__ float  s_cp[B_][2 * NP_];
    __shared__ double P[NP_][2];
    __shared__ double A[NA_][NCOL_];
    __shared__ double f[NA_];
    __shared__ int    s_piv;
    __shared__ double s_pv;
    int tid = threadIdx.x;

    for (int i = tid; i < B_ * 128; i += 256) {
        const float* p = partial + i * PARTS_;
        float s = 0.f;
        #pragma unroll
        for (int j = 0; j < PARTS_; ++j) s += p[j];
        s_feat[i] = s * (1.0f / (float)HW_);
    }
    if (tid < 2 * NP_) ((double*)P)[tid] = (double)init_cp[tid];
    __syncthreads();

    for (int i = tid; i < B_ * 2 * NP_; i += 256) {
        int b = i / (2 * NP_), j = i % (2 * NP_);
        float acc = fc_b[j];
        const float* w  = fc_w + j * 128;
        const float* fe = s_feat + b * 128;
        #pragma unroll 8
        for (int c = 0; c < 128; ++c) acc += fe[c] * w[c];
        float cpv = init_cp[j] + acc;
        s_cp[b][j] = cpv;
        cp_out[b * 2 * NP_ + j] = cpv;   // second tuple output (f32)
    }
    __syncthreads();

    for (int i = tid; i < NA_ * NCOL_; i += 256) {
        int r = i / NCOL_, cc = i % NCOL_;
        double v;
        if (cc < NA_) {
            if (r < NP_ && cc < NP_) {
                double dx = P[r][0] - P[cc][0];
                double dy = P[r][1] - P[cc][1];
                double d2 = dx * dx + dy * dy;
                v = d2 * log(d2 + 1e-6);
            } else if (r < NP_) {
                v = (cc == NP_) ? 1.0 : ((cc == NP_ + 1) ? P[r][0] : P[r][1]);
            } else if (cc < NP_) {
                v = (r == NP_) ? 1.0 : ((r == NP_ + 1) ? P[cc][0] : P[cc][1]);
            } else {
                v = 0.0;
            }
        } else {
            int y = cc - NA_;
            int b = y >> 1, k = y & 1;
            v = (r < NP_) ? (double)s_cp[b][r * 2 + k] : 0.0;
        }
        A[r][cc] = v;
    }
    __syncthreads();

    for (int k = 0; k < NA_; ++k) {
        if (tid == 0) {
            int piv = k; double best = fabs(A[k][k]);
            for (int r = k + 1; r < NA_; ++r) {
                double v = fabs(A[r][k]);
                if (v > best) { best = v; piv = r; }
            }
            s_piv = piv;
        }
        __syncthreads();
        int piv = s_piv;
        if (piv != k) {
            for (int j = tid; j < NCOL_; j += 256) {
                double tmp = A[k][j]; A[k][j] = A[piv][j]; A[piv][j] = tmp;
            }
        }
        __syncthreads();
        if (tid == 0) s_pv = 1.0 / A[k][k];
        __syncthreads();
        double pv = s_pv;
        for (int j = tid; j < NCOL_; j += 256) A[k][j] *= pv;
        __syncthreads();
        if (tid < NA_) f[tid] = A[tid][k];
        __syncthreads();
        for (int i = tid; i < NA_ * NCOL_; i += 256) {
            int r = i / NCOL_, j = i % NCOL_;
            if (r != k) A[r][j] -= f[r] * A[k][j];
        }
        __syncthreads();
    }

    for (int i = tid; i < B_ * NA_ * 2; i += 256) {
        int b = i / (NA_ * 2), rest = i % (NA_ * 2);
        int n = rest >> 1, c = rest & 1;
        Wm[i] = A[n][NA_ + b * 2 + c];
    }
}

// ---------------------------------------------------------------------------
// Kernel 3: fused TPS grid eval (f32 basis) + bilinear grid_sample.
// XCD-contiguous (b = bid&7). NEW: shuffle-dedup of right-column taps —
// the warp is near-identity, so lane i+1's left tap (v00/v10) is almost
// always lane i's right tap (v01/v11). Load 2 taps/channel, reconstruct the
// other 2 via __shfl_down(.,1) with a per-wave validity mask and a rare
// divergent fallback (borders, y0 transitions). Halves gather VMEM instrs.
// ---------------------------------------------------------------------------
__global__ __launch_bounds__(256) void sample_kernel(const float* __restrict__ t,
                                                     const float* __restrict__ init_cp,
                                                     const double* __restrict__ Wm,
                                                     float* __restrict__ out) {
    int b = blockIdx.x & 7;     // XCD-contiguous: batch == XCD
    int y = blockIdx.x >> 3;
    int x = threadIdx.x;

    __shared__ float sW[NA_][2];
    __shared__ float sP[NP_][2];
    if (x < 2 * NA_)
        ((float*)sW)[x] = (float)Wm[(size_t)b * 2 * NA_ + x];
    else if (x < 2 * NA_ + 2 * NP_)
        ((float*)sP)[x - 2 * NA_] = init_cp[x - 2 * NA_];
    __syncthreads();

    float px = -1.0f + (2.0f / (float)(W_ - 1)) * (float)x;
    float py = -1.0f + (2.0f / (float)(H_ - 1)) * (float)y;

    float ax = sW[NP_][0] + px * sW[NP_ + 1][0] + py * sW[NP_ + 2][0];
    float ay = sW[NP_][1] + px * sW[NP_ + 1][1] + py * sW[NP_ + 2][1];
    #pragma unroll
    for (int n = 0; n < NP_; ++n) {
        float dx = px - sP[n][0];
        float dy = py - sP[n][1];
        float d2 = dx * dx + dy * dy;
        float u  = d2 * logf(d2 + 1e-6f);
        ax += u * sW[n][0];
        ay += u * sW[n][1];
    }

    float xf = fminf(fmaxf((ax + 1.0f) * 0.5f * (float)(W_ - 1), 0.0f), (float)(W_ - 1));
    float yf = fminf(fmaxf((ay + 1.0f) * 0.5f * (float)(H_ - 1), 0.0f), (float)(H_ - 1));
    float x0f = floorf(xf), y0f = floorf(yf);
    int x0 = (int)x0f, y0 = (int)y0f;
    int x1 = min(x0 + 1, W_ - 1);
    int y1 = min(y0 + 1, H_ - 1);
    float wx = xf - x0f, wy = yf - y0f;
    float omwx = 1.0f - wx, omwy = 1.0f - wy;

    // shuffle-dedup validity: lane i+1's (x0,y0) must be (x1[i], y0[i])
    int lane = threadIdx.x & 63;
    int nx0 = __shfl_down(x0, 1);
    int ny0 = __shfl_down(y0, 1);
    bool vshfl = (lane != 63) && (nx0 == x1) && (ny0 == y0);

    int i00 = y0 * W_ + x0;
    int i01 = y0 * W_ + x1;
    int i10 = y1 * W_ + x0;
    int i11 = y1 * W_ + x1;

    const float* tb = t   + (size_t)b * C_ * HW_;
    float*       ob = out + (size_t)b * C_ * HW_ + y * W_ + x;

    #pragma unroll 2
    for (int cc = 0; cc < C_; cc += 8) {
        float a00[8], a10[8], a01[8], a11[8];
        #pragma unroll
        for (int j = 0; j < 8; ++j) {
            const float* tc = tb + (size_t)(cc + j) * HW_;
            a00[j] = tc[i00];
            a10[j] = tc[i10];
        }
        #pragma unroll
        for (int j = 0; j < 8; ++j) {
            a01[j] = __shfl_down(a00[j], 1);
            a11[j] = __shfl_down(a10[j], 1);
        }
        if (!vshfl) {
            #pragma unroll
            for (int j = 0; j < 8; ++j) {
                const float* tc = tb + (size_t)(cc + j) * HW_;
                a01[j] = tc[i01];
                a11[j] = tc[i11];
            }
        }
        #pragma unroll
        for (int j = 0; j < 8; ++j) {
            float top = a00[j] * omwx + a01[j] * wx;
            float bot = a10[j] * omwx + a11[j] * wx;
            __builtin_nontemporal_store(top * omwy + bot * wy, ob + (size_t)(cc + j) * HW_);
        }
    }
}

// ---------------------------------------------------------------------------
extern "C" void kernel_launch(void* const* d_in, const int* in_sizes, int n_in,
                              void* d_out, int out_size, void* d_ws, size_t ws_size,
                              hipStream_t stream) {
    const float* t       = (const float*)d_in[0];
    const float* rgb     = (const float*)d_in[1];
    const float* fc_w    = (const float*)d_in[2];
    const float* fc_b    = (const float*)d_in[3];
    const float* init_cp = (const float*)d_in[4];

    float* out    = (float*)d_out;
    float* cp_out = out + (size_t)B_ * C_ * HW_;   // tuple output #2

    float*  partial = (float*)d_ws;                    // 1024*4 f32 = 16 KB
    double* Wm      = (double*)((char*)d_ws + 32768);  // 8*28*2 f64

    mean_partial_kernel<<<2048, 256, 0, stream>>>(t, rgb, partial);
    solve_kernel<<<1, 256, 0, stream>>>(partial, fc_w, fc_b, init_cp, cp_out, Wm);
    sample_kernel<<<B_ * H_, 256, 0, stream>>>(t, init_cp, Wm, out);
}

// Round 8
// 140.133 us; speedup vs baseline: 1.0131x; 1.0131x over previous
//
#include <hip/hip_runtime.h>
#include <hip/hip_bf16.h>

#define B_  8
#define C_  64
#define H_  256
#define W_  256
#define HW_ (H_ * W_)
#define NP_ 25          // NUM_POINTS
#define NA_ 28          // N + 3 (augmented TPS system size)
#define NRHS_ 16        // 8 batches x 2 coords
#define NCOL_ (NA_ + NRHS_)   // 44
#define PARTS_ 4              // chunks per channel
#define CHUNK_ (HW_ / PARTS_) // 16384 floats per chunk

typedef float f32x4 __attribute__((ext_vector_type(4)));

// ---------------------------------------------------------------------------
// Kernel 1: partial sums for per-(b,c) mean of concat([t, rgb]).
// 2048 blocks, fully resident; XCD-contiguous (bid&7 = XCD owns batch b=xcd).
// At the measured ~3.5 TB/s device read wall (268 MB -> ~76 us). Unchanged.
// ---------------------------------------------------------------------------
__global__ __launch_bounds__(256) void mean_partial_kernel(const float* __restrict__ t,
                                                           const float* __restrict__ rgb,
                                                           float* __restrict__ partial) {
    int bid   = blockIdx.x;            // 0..2047
    int xcd   = bid & 7;
    int li    = bid >> 3;              // 0..255 within XCD
    int plane = xcd * 64 + (li >> 2);  // = b*64 + c  (b == xcd)
    int part  = li & 3;
    int b = plane >> 6, c = plane & 63;

    size_t off = (size_t)plane * HW_ + (size_t)part * CHUNK_;
    const f32x4* t4 = (const f32x4*)(t + off);
    const f32x4* r4 = (const f32x4*)(rgb + off);
    int base = threadIdx.x;

    float at = 0.f, ar = 0.f;
    #pragma unroll
    for (int half = 0; half < 2; ++half) {
        f32x4 va[8], vb[8];
        #pragma unroll
        for (int k = 0; k < 8; ++k) va[k] = t4[base + (half * 8 + k) * 256];
        #pragma unroll
        for (int k = 0; k < 8; ++k) vb[k] = __builtin_nontemporal_load(r4 + base + (half * 8 + k) * 256);
        #pragma unroll
        for (int k = 0; k < 8; ++k) {
            at += (va[k].x + va[k].y) + (va[k].z + va[k].w);
            ar += (vb[k].x + vb[k].y) + (vb[k].z + vb[k].w);
        }
    }
    #pragma unroll
    for (int o = 32; o > 0; o >>= 1) {
        at += __shfl_down(at, o);
        ar += __shfl_down(ar, o);
    }
    __shared__ float redt[4], redr[4];
    if ((threadIdx.x & 63) == 0) {
        redt[threadIdx.x >> 6] = at;
        redr[threadIdx.x >> 6] = ar;
    }
    __syncthreads();
    if (threadIdx.x == 0) {
        // feat layout: [b][0:64]=mean(t), [b][64:128]=mean(rgb)
        partial[(b * 128 + c) * PARTS_ + part]      = (redt[0] + redt[1]) + (redt[2] + redt[3]);
        partial[(b * 128 + 64 + c) * PARTS_ + part] = (redr[0] + redr[1]) + (redr[2] + redr[3]);
    }
}

// ---------------------------------------------------------------------------
// Kernel 2: reduce partials -> feat; delta = feat @ fc_w^T + fc_b;
// cp = init_cp + delta (second output); build TPS L (28x28, f64) and
// Gauss-Jordan solve for all 8 batches x 2 coords -> Wm[8][28][2] f64 in ws.
// ---------------------------------------------------------------------------
__global__ __launch_bounds__(256) void solve_kernel(const float* __restrict__ partial,
                                                    const float* __restrict__ fc_w,
                                                    const float* __restrict__ fc_b,
                                                    const float* __restrict__ init_cp,
                                                    float* __restrict__ cp_out,
                                                    double* __restrict__ Wm) {
    __shared__ float  s_feat[B_ * 128];
    __shared__ float  s_cp[B_][2 * NP_];
    __shared__ double P[NP_][2];
    __shared__ double A[NA_][NCOL_];
    __shared__ double f[NA_];
    __shared__ int    s_piv;
    __shared__ double s_pv;
    int tid = threadIdx.x;

    for (int i = tid; i < B_ * 128; i += 256) {
        const float* p = partial + i * PARTS_;
        float s = 0.f;
        #pragma unroll
        for (int j = 0; j < PARTS_; ++j) s += p[j];
        s_feat[i] = s * (1.0f / (float)HW_);
    }
    if (tid < 2 * NP_) ((double*)P)[tid] = (double)init_cp[tid];
    __syncthreads();

    for (int i = tid; i < B_ * 2 * NP_; i += 256) {
        int b = i / (2 * NP_), j = i % (2 * NP_);
        float acc = fc_b[j];
        const float* w  = fc_w + j * 128;
        const float* fe = s_feat + b * 128;
        #pragma unroll 8
        for (int c = 0; c < 128; ++c) acc += fe[c] * w[c];
        float cpv = init_cp[j] + acc;
        s_cp[b][j] = cpv;
        cp_out[b * 2 * NP_ + j] = cpv;   // second tuple output (f32)
    }
    __syncthreads();

    for (int i = tid; i < NA_ * NCOL_; i += 256) {
        int r = i / NCOL_, cc = i % NCOL_;
        double v;
        if (cc < NA_) {
            if (r < NP_ && cc < NP_) {
                double dx = P[r][0] - P[cc][0];
                double dy = P[r][1] - P[cc][1];
                double d2 = dx * dx + dy * dy;
                v = d2 * log(d2 + 1e-6);
            } else if (r < NP_) {
                v = (cc == NP_) ? 1.0 : ((cc == NP_ + 1) ? P[r][0] : P[r][1]);
            } else if (cc < NP_) {
                v = (r == NP_) ? 1.0 : ((r == NP_ + 1) ? P[cc][0] : P[cc][1]);
            } else {
                v = 0.0;
            }
        } else {
            int y = cc - NA_;
            int b = y >> 1, k = y & 1;
            v = (r < NP_) ? (double)s_cp[b][r * 2 + k] : 0.0;
        }
        A[r][cc] = v;
    }
    __syncthreads();

    for (int k = 0; k < NA_; ++k) {
        if (tid == 0) {
            int piv = k; double best = fabs(A[k][k]);
            for (int r = k + 1; r < NA_; ++r) {
                double v = fabs(A[r][k]);
                if (v > best) { best = v; piv = r; }
            }
            s_piv = piv;
        }
        __syncthreads();
        int piv = s_piv;
        if (piv != k) {
            for (int j = tid; j < NCOL_; j += 256) {
                double tmp = A[k][j]; A[k][j] = A[piv][j]; A[piv][j] = tmp;
            }
        }
        __syncthreads();
        if (tid == 0) s_pv = 1.0 / A[k][k];
        __syncthreads();
        double pv = s_pv;
        for (int j = tid; j < NCOL_; j += 256) A[k][j] *= pv;
        __syncthreads();
        if (tid < NA_) f[tid] = A[tid][k];
        __syncthreads();
        for (int i = tid; i < NA_ * NCOL_; i += 256) {
            int r = i / NCOL_, j = i % NCOL_;
            if (r != k) A[r][j] -= f[r] * A[k][j];
        }
        __syncthreads();
    }

    for (int i = tid; i < B_ * NA_ * 2; i += 256) {
        int b = i / (NA_ * 2), rest = i % (NA_ * 2);
        int n = rest >> 1, c = rest & 1;
        Wm[i] = A[n][NA_ + b * 2 + c];
    }
}

// ---------------------------------------------------------------------------
// Kernel 3: fused TPS grid eval (f32 basis) + bilinear grid_sample.
// XCD-contiguous (b = bid&7). r7's shuffle-dedup reverted (regressed).
// NEW: output staged per 8-channel group in LDS, then emitted as float4
// nontemporal stores (4x fewer write requests, copy-like bursts) — tests
// whether scalar-store request inefficiency is what holds sample at
// 2.35+2.35 TB/s vs the 3.15+3.15 TB/s float4-copy ceiling.
// ---------------------------------------------------------------------------
__global__ __launch_bounds__(256) void sample_kernel(const float* __restrict__ t,
                                                     const float* __restrict__ init_cp,
                                                     const double* __restrict__ Wm,
                                                     float* __restrict__ out) {
    int b = blockIdx.x & 7;     // XCD-contiguous: batch == XCD
    int y = blockIdx.x >> 3;
    int x = threadIdx.x;

    __shared__ float sW[NA_][2];
    __shared__ float sP[NP_][2];
    __shared__ float lds[8][256];   // one 8-channel group of the output row
    if (x < 2 * NA_)
        ((float*)sW)[x] = (float)Wm[(size_t)b * 2 * NA_ + x];
    else if (x < 2 * NA_ + 2 * NP_)
        ((float*)sP)[x - 2 * NA_] = init_cp[x - 2 * NA_];
    __syncthreads();

    float px = -1.0f + (2.0f / (float)(W_ - 1)) * (float)x;
    float py = -1.0f + (2.0f / (float)(H_ - 1)) * (float)y;

    float ax = sW[NP_][0] + px * sW[NP_ + 1][0] + py * sW[NP_ + 2][0];
    float ay = sW[NP_][1] + px * sW[NP_ + 1][1] + py * sW[NP_ + 2][1];
    #pragma unroll
    for (int n = 0; n < NP_; ++n) {
        float dx = px - sP[n][0];
        float dy = py - sP[n][1];
        float d2 = dx * dx + dy * dy;
        float u  = d2 * logf(d2 + 1e-6f);
        ax += u * sW[n][0];
        ay += u * sW[n][1];
    }

    float xf = fminf(fmaxf((ax + 1.0f) * 0.5f * (float)(W_ - 1), 0.0f), (float)(W_ - 1));
    float yf = fminf(fmaxf((ay + 1.0f) * 0.5f * (float)(H_ - 1), 0.0f), (float)(H_ - 1));
    float x0f = floorf(xf), y0f = floorf(yf);
    int x0 = (int)x0f, y0 = (int)y0f;
    int x1 = min(x0 + 1, W_ - 1);
    int y1 = min(y0 + 1, H_ - 1);
    float wx = xf - x0f, wy = yf - y0f;
    float omwx = 1.0f - wx, omwy = 1.0f - wy;

    int i00 = y0 * W_ + x0;
    int i01 = y0 * W_ + x1;
    int i10 = y1 * W_ + x0;
    int i11 = y1 * W_ + x1;

    const float* tb = t   + (size_t)b * C_ * HW_;
    float*       ob = out + (size_t)b * C_ * HW_ + (size_t)y * W_;

    for (int cc = 0; cc < C_; cc += 8) {
        float a00[8], a01[8], a10[8], a11[8];
        #pragma unroll
        for (int j = 0; j < 8; ++j) {
            const float* tc = tb + (size_t)(cc + j) * HW_;
            a00[j] = tc[i00];
            a01[j] = tc[i01];
            a10[j] = tc[i10];
            a11[j] = tc[i11];
        }
        #pragma unroll
        for (int j = 0; j < 8; ++j) {
            float top = a00[j] * omwx + a01[j] * wx;
            float bot = a10[j] * omwx + a11[j] * wx;
            lds[j][x] = top * omwy + bot * wy;
        }
        __syncthreads();
        // emit 8 channel-rows (2048 floats) as 512 float4 NT stores
        #pragma unroll
        for (int k = 0; k < 2; ++k) {
            int idx = x + k * 256;          // 0..511
            int j   = idx >> 6;             // channel within group
            int xq  = idx & 63;             // float4 index within row
            f32x4 v = *(const f32x4*)&lds[j][xq * 4];
            __builtin_nontemporal_store(v, (f32x4*)(ob + (size_t)(cc + j) * HW_ + xq * 4));
        }
        __syncthreads();
    }
}

// ---------------------------------------------------------------------------
extern "C" void kernel_launch(void* const* d_in, const int* in_sizes, int n_in,
                              void* d_out, int out_size, void* d_ws, size_t ws_size,
                              hipStream_t stream) {
    const float* t       = (const float*)d_in[0];
    const float* rgb     = (const float*)d_in[1];
    const float* fc_w    = (const float*)d_in[2];
    const float* fc_b    = (const float*)d_in[3];
    const float* init_cp = (const float*)d_in[4];

    float* out    = (float*)d_out;
    float* cp_out = out + (size_t)B_ * C_ * HW_;   // tuple output #2

    float*  partial = (float*)d_ws;                    // 1024*4 f32 = 16 KB
    double* Wm      = (double*)((char*)d_ws + 32768);  // 8*28*2 f64

    mean_partial_kernel<<<2048, 256, 0, stream>>>(t, rgb, partial);
    solve_kernel<<<1, 256, 0, stream>>>(partial, fc_w, fc_b, init_cp, cp_out, Wm);
    sample_kernel<<<B_ * H_, 256, 0, stream>>>(t, init_cp, Wm, out);
}